// Round 2
// baseline (202.868 us; speedup 1.0000x reference)
//
#include <hip/hip_runtime.h>
#include <cmath>

#define N_QUERY 16384
#define N_VOX   8192
#define Q_ROWS  4          // query rows per block
#define BLOCK   512        // threads per block (8 waves)
#define VPT     16         // voxels per thread = N_VOX / BLOCK
#define NGROUP  4          // groups of 4 voxels per thread (VPT/4)

typedef float f32x4 __attribute__((ext_vector_type(4)));

#if __has_builtin(__builtin_amdgcn_exp2f)
__device__ __forceinline__ float fast_exp2(float x) { return __builtin_amdgcn_exp2f(x); }
#else
__device__ __forceinline__ float fast_exp2(float x) { float r; asm("v_exp_f32 %0, %1" : "=v"(r) : "v"(x)); return r; }
#endif

#if __has_builtin(__builtin_amdgcn_sqrtf)
__device__ __forceinline__ float fast_sqrt(float x) { return __builtin_amdgcn_sqrtf(x); }
#else
__device__ __forceinline__ float fast_sqrt(float x) { float r; asm("v_sqrt_f32 %0, %1" : "=v"(r) : "v"(x)); return r; }
#endif

__device__ __forceinline__ float wave_reduce_sum(float v) {
    #pragma unroll
    for (int off = 32; off > 0; off >>= 1) v += __shfl_xor(v, off, 64);
    return v;
}

__global__ __launch_bounds__(BLOCK)
void voxel_interp_kernel(const float* __restrict__ qp,   // [N,3]
                         const float* __restrict__ vc,   // [M,3]
                         const float* __restrict__ vf,   // [M,4]
                         const float* __restrict__ vs,   // [M]
                         float* __restrict__ dens,       // [N]
                         float* __restrict__ cols,       // [N,3]
                         float* __restrict__ sizes,      // [N]
                         float* __restrict__ wout)       // [N,M]
{
    const int t = threadIdx.x;
    const int rowbase = blockIdx.x * Q_ROWS;

    // ---- load the Q query points (uniform across block -> scalar loads) ----
    float qx[Q_ROWS], qy[Q_ROWS], qz[Q_ROWS];
    #pragma unroll
    for (int q = 0; q < Q_ROWS; ++q) {
        qx[q] = qp[(rowbase + q) * 3 + 0];
        qy[q] = qp[(rowbase + q) * 3 + 1];
        qz[q] = qp[(rowbase + q) * 3 + 2];
    }

    float w[Q_ROWS][VPT];                 // unnormalized weights (registers)
    float asum[Q_ROWS];
    float af0[Q_ROWS], af1[Q_ROWS], af2[Q_ROWS], af3[Q_ROWS];
    float asz[Q_ROWS];
    #pragma unroll
    for (int q = 0; q < Q_ROWS; ++q) {
        asum[q] = 0.f; af0[q] = 0.f; af1[q] = 0.f; af2[q] = 0.f; af3[q] = 0.f; asz[q] = 0.f;
    }

    const float NEG_HALF_LOG2E = -0.7213475204444817f;  // -log2(e)/2  (sigma=1)

    // ---- main pass: each thread owns 4 groups of 4 consecutive voxels ----
    #pragma unroll
    for (int g = 0; g < NGROUP; ++g) {
        const int v0 = g * (N_VOX / NGROUP) + t * 4;   // 16B-aligned everywhere
        // 4 voxels * 3 coords = 12 contiguous floats -> 3x float4
        const float4* cp = reinterpret_cast<const float4*>(vc + (size_t)v0 * 3);
        float4 c0 = cp[0], c1 = cp[1], c2 = cp[2];
        float cxs[4] = {c0.x, c0.w, c1.z, c2.y};
        float cys[4] = {c0.y, c1.x, c1.w, c2.z};
        float czs[4] = {c0.z, c1.y, c2.x, c2.w};
        const float4* fp = reinterpret_cast<const float4*>(vf + (size_t)v0 * 4);
        float4 f0 = fp[0], f1 = fp[1], f2 = fp[2], f3 = fp[3];
        float4 fa[4] = {f0, f1, f2, f3};
        float4 sz4 = *reinterpret_cast<const float4*>(vs + v0);
        float szs[4] = {sz4.x, sz4.y, sz4.z, sz4.w};

        #pragma unroll
        for (int i = 0; i < 4; ++i) {
            const float cx = cxs[i], cy = cys[i], cz = czs[i];
            #pragma unroll
            for (int q = 0; q < Q_ROWS; ++q) {
                float dx = qx[q] - cx;
                float dy = qy[q] - cy;
                float dz = qz[q] - cz;
                float d2 = dx * dx + dy * dy + dz * dz;   // exact, >= 0
                float d  = fast_sqrt(d2);
                float ww = fast_exp2(d * NEG_HALF_LOG2E); // exp(-d/2)
                w[q][g * 4 + i] = ww;
                asum[q] += ww;
                af0[q] += ww * fa[i].x;
                af1[q] += ww * fa[i].y;
                af2[q] += ww * fa[i].z;
                af3[q] += ww * fa[i].w;
                asz[q] += ww * szs[i];
            }
        }
    }

    // ---- block reduction of 24 values (sum, f0..f3, size) x Q_ROWS ----
    float vals[Q_ROWS * 6];
    #pragma unroll
    for (int q = 0; q < Q_ROWS; ++q) {
        vals[q * 6 + 0] = asum[q];
        vals[q * 6 + 1] = af0[q];
        vals[q * 6 + 2] = af1[q];
        vals[q * 6 + 3] = af2[q];
        vals[q * 6 + 4] = af3[q];
        vals[q * 6 + 5] = asz[q];
    }

    __shared__ float red[BLOCK / 64][Q_ROWS * 6];
    __shared__ float fin[Q_ROWS * 6];
    const int wave = t >> 6;
    const int lane = t & 63;
    #pragma unroll
    for (int i = 0; i < Q_ROWS * 6; ++i) {
        float r = wave_reduce_sum(vals[i]);
        if (lane == 0) red[wave][i] = r;
    }
    __syncthreads();
    if (t < Q_ROWS * 6) {
        float s = 0.f;
        #pragma unroll
        for (int wv = 0; wv < BLOCK / 64; ++wv) s += red[wv][t];
        fin[t] = s;
    }
    __syncthreads();

    float inv[Q_ROWS];
    #pragma unroll
    for (int q = 0; q < Q_ROWS; ++q) {
        inv[q] = 1.0f / (fin[q * 6 + 0] + 1e-8f);   // LDS broadcast read
    }

    // ---- streaming write of normalized weights (non-temporal float4) ----
    #pragma unroll
    for (int q = 0; q < Q_ROWS; ++q) {
        const float iv = inv[q];
        float* base = wout + (size_t)(rowbase + q) * N_VOX;
        #pragma unroll
        for (int g = 0; g < NGROUP; ++g) {
            const int v0 = g * (N_VOX / NGROUP) + t * 4;
            f32x4 o;
            o.x = w[q][g * 4 + 0] * iv;
            o.y = w[q][g * 4 + 1] * iv;
            o.z = w[q][g * 4 + 2] * iv;
            o.w = w[q][g * 4 + 3] * iv;
            __builtin_nontemporal_store(o, reinterpret_cast<f32x4*>(base + v0));
        }
    }

    // ---- tiny per-row outputs ----
    if (t < Q_ROWS) {
        const int q = t;
        const int row = rowbase + q;
        const float iv = inv[q];
        const float f0 = fin[q * 6 + 1] * iv;
        const float f1 = fin[q * 6 + 2] * iv;
        const float f2 = fin[q * 6 + 3] * iv;
        const float f3 = fin[q * 6 + 4] * iv;
        const float sz = fin[q * 6 + 5] * iv;
        dens[row] = log1pf(expf(f0));                 // softplus
        cols[row * 3 + 0] = 1.0f / (1.0f + expf(-f1));  // sigmoid
        cols[row * 3 + 1] = 1.0f / (1.0f + expf(-f2));
        cols[row * 3 + 2] = 1.0f / (1.0f + expf(-f3));
        sizes[row] = sz;
    }
}

extern "C" void kernel_launch(void* const* d_in, const int* in_sizes, int n_in,
                              void* d_out, int out_size, void* d_ws, size_t ws_size,
                              hipStream_t stream) {
    const float* qp = (const float*)d_in[0];   // query_points [16384,3]
    const float* vc = (const float*)d_in[1];   // voxel_coords [8192,3]
    const float* vf = (const float*)d_in[2];   // voxel_features [8192,4]
    const float* vs = (const float*)d_in[3];   // voxel_sizes [8192]

    float* out   = (float*)d_out;
    float* dens  = out;                         // [16384]
    float* cols  = out + N_QUERY;               // [16384,3]
    float* sizes = out + N_QUERY * 4;           // [16384]
    float* wout  = out + N_QUERY * 5;           // [16384,8192]

    dim3 grid(N_QUERY / Q_ROWS);
    voxel_interp_kernel<<<grid, BLOCK, 0, stream>>>(qp, vc, vf, vs, dens, cols, sizes, wout);
}